// Round 1
// 232.741 us; speedup vs baseline: 1.0164x; 1.0164x over previous
//
#include <hip/hip_runtime.h>
#include <stdint.h>

// ---------------------------------------------------------------------------
// PatchEmbed + HMQConv2d fake-quant, fp32 I/O.
//   s_x = max(max|x|,1e-8)/127 ; s_w = max(max|w|,1e-8)/127
//   out[b, gx*28+gy, d] = (sum_k qx*qw) * s_x*s_w + bias[d]
// GEMM M=50176, N=768, K=192; integer codes (|q|<=127) in bf16 MFMA = exact.
//
// Round-6 (polish): pipeline was 3-4x above its ~55us traffic floor.
//  (a) finalize_k removed: 1088-partial reduce folded into quant prologue
//      (redundant per block, L2-hot, ~free); quant block 0 publishes slots.
//  (b) quant re-tiled by (b,gx) + 11KB LDS transpose: x reads coalesced
//      (896B rows) AND Aq written as one contiguous 10.5KB stream per block
//      (was: 16B scatter at 384B stride = 64 lines per wave store).
//  (c) gemm epilogue: per-wave LDS transpose (b128 col-major writes, scalar
//      row reads) -> 16 dwordx4 stores/thread instead of 64 scalar dwords
//      against the 154MB output stream. Barrier-free: wave-local LDS ops
//      are in-order; explicit lgkmcnt(0) guards the write->read edge.
// ---------------------------------------------------------------------------

typedef short bf16x8 __attribute__((ext_vector_type(8)));  // 8 bf16 codes
using f32x4 = __attribute__((ext_vector_type(4))) float;

static __device__ __forceinline__ uint16_t f2bfbits(float f) {
  uint32_t u = __float_as_uint(f);
  u += 0x7FFFu + ((u >> 16) & 1u);   // RTNE (exact for small ints)
  return (uint16_t)(u >> 16);
}
static __device__ __forceinline__ uint32_t q2(float a, float b, float inv_s) {
  float qa = rintf(fminf(fmaxf(a * inv_s, -127.0f), 127.0f));
  float qb = rintf(fminf(fmaxf(b * inv_s, -127.0f), 127.0f));
  return (uint32_t)f2bfbits(qa) | ((uint32_t)f2bfbits(qb) << 16);
}
static __device__ __forceinline__ uint4 quant8(float4 a0, float4 a1, float inv_s) {
  uint4 q;
  q.x = q2(a0.x, a0.y, inv_s);
  q.y = q2(a0.z, a0.w, inv_s);
  q.z = q2(a1.x, a1.y, inv_s);
  q.w = q2(a1.z, a1.w, inv_s);
  return q;
}

// ---- absmax: blocks [0,1024) cover x, [1024,1088) cover w -----------------
#define NBX 1024
#define NBW 64
__global__ void absmax_k(const float4* __restrict__ x, int nx4,
                         const float4* __restrict__ w, int nw4,
                         float* __restrict__ partials) {
  __shared__ float red[4];
  float m = 0.0f;
  if (blockIdx.x < NBX) {
    for (int i = blockIdx.x * 256 + threadIdx.x; i < nx4; i += NBX * 256) {
      float4 u = x[i];
      m = fmaxf(m, fabsf(u.x)); m = fmaxf(m, fabsf(u.y));
      m = fmaxf(m, fabsf(u.z)); m = fmaxf(m, fabsf(u.w));
    }
  } else {
    for (int i = (blockIdx.x - NBX) * 256 + threadIdx.x; i < nw4; i += NBW * 256) {
      float4 u = w[i];
      m = fmaxf(m, fabsf(u.x)); m = fmaxf(m, fabsf(u.y));
      m = fmaxf(m, fabsf(u.z)); m = fmaxf(m, fabsf(u.w));
    }
  }
#pragma unroll
  for (int off = 32; off > 0; off >>= 1) m = fmaxf(m, __shfl_down(m, off, 64));
  if ((threadIdx.x & 63) == 0) red[threadIdx.x >> 6] = m;
  __syncthreads();
  if (threadIdx.x == 0) {
    m = fmaxf(fmaxf(red[0], red[1]), fmaxf(red[2], red[3]));
    partials[blockIdx.x] = m;
  }
}

// ---- quant both ------------------------------------------------------------
// x blocks [0,1792): block = (b,gx). Stage the 28 Aq rows (m = b*784+gx*28+gy)
// through LDS so global reads (x rows, 896B) AND Aq writes (10.5KB stream)
// are both fully coalesced. w blocks [1792,1864): flat, already coalesced.
// Prologue (all blocks): reduce absmax partials -> s_x, s_w in-registers.
#define NQXB 1792
#define NQWB 72
__global__ __launch_bounds__(256) void quant_xw_k(
    const float* __restrict__ x, const float4* __restrict__ w4,
    uint4* __restrict__ Aq, uint4* __restrict__ Wq,
    const float* __restrict__ partials, float* __restrict__ slots) {
  __shared__ float redx[4];
  __shared__ float redw_s;
  __shared__ uint4 stg[28 * 25];   // [gy][octet], row padded 24->25 uint4
  const int tid = threadIdx.x;

  // ---- scales (every block; partials are tiny and L2-hot) ----
  float mx = 0.0f;
  for (int i = tid; i < NBX; i += 256) mx = fmaxf(mx, partials[i]);
#pragma unroll
  for (int off = 32; off > 0; off >>= 1) mx = fmaxf(mx, __shfl_down(mx, off, 64));
  if ((tid & 63) == 0) redx[tid >> 6] = mx;
  if (tid < 64) {
    float mw = partials[NBX + tid];
#pragma unroll
    for (int off = 32; off > 0; off >>= 1) mw = fmaxf(mw, __shfl_down(mw, off, 64));
    if (tid == 0) redw_s = mw;
  }
  __syncthreads();
  float sx = fmaxf(fmaxf(redx[0], redx[1]), fmaxf(redx[2], redx[3]));
  sx = fmaxf(sx, 1e-8f) * (1.0f / 127.0f);
  float sw = fmaxf(redw_s, 1e-8f) * (1.0f / 127.0f);
  if (blockIdx.x == 0 && tid == 0) { slots[0] = sx; slots[1] = sw; }

  if (blockIdx.x < NQXB) {
    const float inv = 1.0f / sx;
    const int b  = blockIdx.x / 28;
    const int gx = blockIdx.x - b * 28;
    // 672 octet tasks: r = c*8+p (x row), gy = patch col. Reads coalesced.
    for (int t = tid; t < 672; t += 256) {
      const int r  = t / 28;            // 0..23  (= Aq octet index c*8+p)
      const int gy = t - r * 28;        // 0..27
      const int c = r >> 3, p = r & 7;
      const float4* src =
          (const float4*)(x + (size_t)((b * 3 + c) * 224 + gx * 8 + p) * 224);
      float4 a0 = src[gy * 2], a1 = src[gy * 2 + 1];
      stg[gy * 25 + r] = quant8(a0, a1, inv);
    }
    __syncthreads();
    // contiguous stream-out: Aq rows m = b*784+gx*28 + [0,28), 672 uint4
    uint4* dst = Aq + (size_t)(b * 784 + gx * 28) * 24;
    for (int t = tid; t < 672; t += 256) {
      const int gy = t / 24;
      dst[t] = stg[gy * 25 + (t - gy * 24)];
    }
  } else {
    const float inv = 1.0f / sw;
    const int g = (blockIdx.x - NQXB) * 256 + tid;   // < 18,432
    float4 a0 = w4[g * 2], a1 = w4[g * 2 + 1];
    Wq[g] = quant8(a0, a1, inv);                     // flat order == [d][k]
  }
}

// ---------------------------------------------------------------------------
// Pure code-GEMM. mfma_f32_16x16x32_bf16 verified layouts (m89/m120):
//   A frag: A[m = lane&15][k = (lane>>4)*8 + j]  -> Aq uint4 @ m*24 + k/8
//   B frag: W[n = lane&15][k = (lane>>4)*8 + j]  -> Wq uint4 @ n*24 + k/8
//   D:      row = (lane>>4)*4 + reg, col = lane&15
// Epilogue: per-wave LDS transpose -> float4 stores (coalesced 256B runs).
// ---------------------------------------------------------------------------
__global__ __launch_bounds__(256) void gemm_k(
    const uint4* __restrict__ Aq, const uint4* __restrict__ Wq,
    const float* __restrict__ bias, const float* __restrict__ slots,
    float* __restrict__ out) {
  __shared__ float tr[4 * 1280];       // per wave: 64 cols x 20 (16 rows+pad)
  const int tid  = threadIdx.x;
  const int lane = tid & 63;
  const int wid  = tid >> 6;
  const int wm   = wid >> 1;   // 0..1
  const int wn   = wid & 1;    // 0..1
  const int lm   = lane & 15;
  const int lq   = lane >> 4;  // 0..3
  const int m0   = blockIdx.x * 128;   // 392 m-tiles (392%8==0 -> XCD-local)
  const int n0   = blockIdx.y * 128;   // 6 n-tiles

  int abase[4], bbase[4];
#pragma unroll
  for (int tm = 0; tm < 4; ++tm)
    abase[tm] = (m0 + wm * 64 + tm * 16 + lm) * 24 + lq;
#pragma unroll
  for (int tn = 0; tn < 4; ++tn)
    bbase[tn] = (n0 + wn * 64 + tn * 16 + lm) * 24 + lq;

  f32x4 acc[4][4] = {};

#pragma unroll
  for (int ks = 0; ks < 6; ++ks) {     // k-octet index = ks*4 + lq
    bf16x8 af[4], bf[4];
#pragma unroll
    for (int tm = 0; tm < 4; ++tm)
      af[tm] = __builtin_bit_cast(bf16x8, Aq[abase[tm] + ks * 4]);
#pragma unroll
    for (int tn = 0; tn < 4; ++tn)
      bf[tn] = __builtin_bit_cast(bf16x8, Wq[bbase[tn] + ks * 4]);
#pragma unroll
    for (int tm = 0; tm < 4; ++tm)
#pragma unroll
      for (int tn = 0; tn < 4; ++tn)
        acc[tm][tn] = __builtin_amdgcn_mfma_f32_16x16x32_bf16(
            af[tm], bf[tn], acc[tm][tn], 0, 0, 0);
  }

  // ---- epilogue: wave-local transpose, float4 stores ----
  const float scale = slots[0] * slots[1];
  float* T = &tr[wid * 1280];
  const int c4 = lane & 15;                       // float4-column group
  const int gc = n0 + wn * 64 + c4 * 4;
  const float4 bv = *(const float4*)&bias[gc];    // hoisted: c4 fixed per lane

#pragma unroll
  for (int tm = 0; tm < 4; ++tm) {
#pragma unroll
    for (int tn = 0; tn < 4; ++tn)   // element (row=lq*4+j, col=tn*16+lm)
      *(f32x4*)&T[(tn * 16 + lm) * 20 + lq * 4] = acc[tm][tn];
    asm volatile("s_waitcnt lgkmcnt(0)" ::: "memory");
#pragma unroll
    for (int i = 0; i < 4; ++i) {
      const int s = (lane >> 4) + i * 4;          // row 0..15 of this stripe
      float4 v;
      v.x = T[(c4 * 4 + 0) * 20 + s];
      v.y = T[(c4 * 4 + 1) * 20 + s];
      v.z = T[(c4 * 4 + 2) * 20 + s];
      v.w = T[(c4 * 4 + 3) * 20 + s];
      float4 o;
      o.x = fmaf(v.x, scale, bv.x);
      o.y = fmaf(v.y, scale, bv.y);
      o.z = fmaf(v.z, scale, bv.z);
      o.w = fmaf(v.w, scale, bv.w);
      const int gm = m0 + wm * 64 + tm * 16 + s;
      *(float4*)&out[(size_t)gm * 768 + gc] = o;
    }
    asm volatile("s_waitcnt lgkmcnt(0)" ::: "memory");  // reads done before next tm rewrites T
  }
}

// ---------------------------------------------------------------------------

extern "C" void kernel_launch(void* const* d_in, const int* in_sizes, int n_in,
                              void* d_out, int out_size, void* d_ws, size_t ws_size,
                              hipStream_t stream) {
  const float* xf = (const float*)d_in[0];       // 9,633,792 fp32
  const float4* x4 = (const float4*)d_in[0];
  const float4* w4 = (const float4*)d_in[1];     //   147,456 fp32
  const float* bias = (const float*)d_in[2];     //       768 fp32
  float* out = (float*)d_out;                    // 38,535,168 fp32

  char* ws = (char*)d_ws;
  float* slots    = (float*)ws;                  // [0]=s_x, [1]=s_w
  float* partials = (float*)(ws + 256);          // 1088 floats
  uint4* Wq       = (uint4*)(ws + 8192);         //   294,912 B of bf16 codes
  uint4* Aq       = (uint4*)(ws + 8192 + 294912);// 19,267,584 B of bf16 codes

  const int nx4 = 9633792 / 4;   // 2,408,448
  const int nw4 = 147456 / 4;    //    36,864

  absmax_k<<<NBX + NBW, 256, 0, stream>>>(x4, nx4, w4, nw4, partials);
  quant_xw_k<<<NQXB + NQWB, 256, 0, stream>>>(xf, w4, Aq, Wq, partials, slots);
  gemm_k<<<dim3(392, 6), 256, 0, stream>>>(Aq, Wq, bias, slots, out);
}

// Round 2
// 200.314 us; speedup vs baseline: 1.1810x; 1.1619x over previous
//
#include <hip/hip_runtime.h>
#include <stdint.h>

// ---------------------------------------------------------------------------
// PatchEmbed + HMQConv2d fake-quant, fp32 I/O.
//   s_x = max(max|x|,1e-8)/127 ; s_w = max(max|w|,1e-8)/127
//   out[b, gx*28+gy, d] = (sum_k qx*qw) * s_x*s_w + bias[d]
// GEMM M=50176, N=768, K=192.
//
// Round-7: int8 code buffers + mfma_i32_16x16x64_i8 (exact: |acc| <= 192*127^2
// << 2^31). vs round-6 bf16 codes:
//   - Aq 19.3MB -> 9.6MB: quant writes and gemm fetches both halve.
//   - GEMM: 48 MFMA + 24 dwordx4 loads per wave (was 96 + 48); K=192 = 3x64.
//   - i32 acc -> f32 convert folded into the existing LDS-transpose epilogue.
// Pedestal theory (R4/R5/R6 post-mortems): timed region carries ~180us of
// harness re-poison fills; kernel budget is ~50us vs ~43us traffic floor.
// This round attacks the only reducible term left (Aq bytes + MFMA cycles).
// ---------------------------------------------------------------------------

using f32x4 = __attribute__((ext_vector_type(4))) float;
using i32x4 = __attribute__((ext_vector_type(4))) int;

static __device__ __forceinline__ uint32_t q4i8(float4 v, float inv_s) {
  // 4 floats -> 4 int8 codes packed LE (byte 0 = v.x)
  uint32_t r;
  int q0 = (int)rintf(fminf(fmaxf(v.x * inv_s, -127.0f), 127.0f));
  int q1 = (int)rintf(fminf(fmaxf(v.y * inv_s, -127.0f), 127.0f));
  int q2 = (int)rintf(fminf(fmaxf(v.z * inv_s, -127.0f), 127.0f));
  int q3 = (int)rintf(fminf(fmaxf(v.w * inv_s, -127.0f), 127.0f));
  r = (uint32_t)(q0 & 0xff) | ((uint32_t)(q1 & 0xff) << 8) |
      ((uint32_t)(q2 & 0xff) << 16) | ((uint32_t)(q3 & 0xff) << 24);
  return r;
}

// ---- absmax: blocks [0,1024) cover x, [1024,1088) cover w -----------------
#define NBX 1024
#define NBW 64
__global__ void absmax_k(const float4* __restrict__ x, int nx4,
                         const float4* __restrict__ w, int nw4,
                         float* __restrict__ partials) {
  __shared__ float red[4];
  float m = 0.0f;
  if (blockIdx.x < NBX) {
    for (int i = blockIdx.x * 256 + threadIdx.x; i < nx4; i += NBX * 256) {
      float4 u = x[i];
      m = fmaxf(m, fabsf(u.x)); m = fmaxf(m, fabsf(u.y));
      m = fmaxf(m, fabsf(u.z)); m = fmaxf(m, fabsf(u.w));
    }
  } else {
    for (int i = (blockIdx.x - NBX) * 256 + threadIdx.x; i < nw4; i += NBW * 256) {
      float4 u = w[i];
      m = fmaxf(m, fabsf(u.x)); m = fmaxf(m, fabsf(u.y));
      m = fmaxf(m, fabsf(u.z)); m = fmaxf(m, fabsf(u.w));
    }
  }
#pragma unroll
  for (int off = 32; off > 0; off >>= 1) m = fmaxf(m, __shfl_down(m, off, 64));
  if ((threadIdx.x & 63) == 0) red[threadIdx.x >> 6] = m;
  __syncthreads();
  if (threadIdx.x == 0) {
    m = fmaxf(fmaxf(red[0], red[1]), fmaxf(red[2], red[3]));
    partials[blockIdx.x] = m;
  }
}

// ---- quant both ------------------------------------------------------------
// x blocks [0,1792): block = (b,gx). Stage 28 Aq rows (m = b*784+gx*28+gy,
// 192 int8 each) through LDS: x reads coalesced (consecutive gy = consecutive
// 32B of an x row), Aq written as one contiguous 5376B stream per block.
// w blocks [1792,1828): 16 floats/thread -> uint4 int8 stores, flat [d][k].
// Prologue (all blocks): reduce absmax partials -> s_x, s_w in-registers
// (1088 floats, L2-hot, ~free); block 0 publishes slots for the gemm.
#define NQXB 1792
#define NQWB 36
__global__ __launch_bounds__(256) void quant_xw_k(
    const float* __restrict__ x, const float4* __restrict__ w4,
    uint4* __restrict__ Aq, uint4* __restrict__ Wq,
    const float* __restrict__ partials, float* __restrict__ slots) {
  __shared__ float redx[4];
  __shared__ float redw_s;
  __shared__ uint2 stg8[28][26];   // [gy][octet], row padded 24->26 uint2
  const int tid = threadIdx.x;

  // ---- scales (every block) ----
  float mx = 0.0f;
  for (int i = tid; i < NBX; i += 256) mx = fmaxf(mx, partials[i]);
#pragma unroll
  for (int off = 32; off > 0; off >>= 1) mx = fmaxf(mx, __shfl_down(mx, off, 64));
  if ((tid & 63) == 0) redx[tid >> 6] = mx;
  if (tid < 64) {
    float mw = partials[NBX + tid];
#pragma unroll
    for (int off = 32; off > 0; off >>= 1) mw = fmaxf(mw, __shfl_down(mw, off, 64));
    if (tid == 0) redw_s = mw;
  }
  __syncthreads();
  float sx = fmaxf(fmaxf(redx[0], redx[1]), fmaxf(redx[2], redx[3]));
  sx = fmaxf(sx, 1e-8f) * (1.0f / 127.0f);
  float sw = fmaxf(redw_s, 1e-8f) * (1.0f / 127.0f);
  if (blockIdx.x == 0 && tid == 0) { slots[0] = sx; slots[1] = sw; }

  if (blockIdx.x < NQXB) {
    const float inv = 1.0f / sx;
    const int b  = blockIdx.x / 28;
    const int gx = blockIdx.x - b * 28;
    // 672 octet tasks: r = c*8+p (x row / k-octet), gy = patch col.
    for (int t = tid; t < 672; t += 256) {
      const int r  = t / 28;            // 0..23  (k bytes [8r, 8r+8))
      const int gy = t - r * 28;        // 0..27
      const int c = r >> 3, p = r & 7;
      const float4* src =
          (const float4*)(x + (size_t)((b * 3 + c) * 224 + gx * 8 + p) * 224);
      float4 a0 = src[gy * 2], a1 = src[gy * 2 + 1];
      uint2 q;
      q.x = q4i8(a0, inv);
      q.y = q4i8(a1, inv);
      stg8[gy][r] = q;
    }
    __syncthreads();
    // contiguous stream-out: rows m = b*784+gx*28 + [0,28), 28*12 uint4
    uint4* dst = Aq + (size_t)(b * 784 + gx * 28) * 12;
    for (int t = tid; t < 336; t += 256) {
      const int gy = t / 12;
      const int j  = t - gy * 12;
      uint2 lo = stg8[gy][2 * j], hi = stg8[gy][2 * j + 1];
      uint4 v; v.x = lo.x; v.y = lo.y; v.z = hi.x; v.w = hi.y;
      dst[t] = v;
    }
  } else {
    const float inv = 1.0f / sw;
    const int g = (blockIdx.x - NQXB) * 256 + tid;   // < 9,216
    float4 a0 = w4[g * 4], a1 = w4[g * 4 + 1];
    float4 a2 = w4[g * 4 + 2], a3 = w4[g * 4 + 3];
    uint4 q;
    q.x = q4i8(a0, inv); q.y = q4i8(a1, inv);
    q.z = q4i8(a2, inv); q.w = q4i8(a3, inv);
    Wq[g] = q;                                       // flat order == [d][k]
  }
}

// ---------------------------------------------------------------------------
// Pure int8 code-GEMM, mfma_i32_16x16x64_i8 (K=192 = 3 steps).
// Layouts (byte-extension of verified bf16 maps, C/D dtype-independent):
//   A frag: A[m = lane&15][k = (lane>>4)*16 + j] -> uint4 @ m*12 + lq + ks*4
//   B frag: W[n = lane&15][k = (lane>>4)*16 + j] -> uint4 @ n*12 + lq + ks*4
//   D:      row = (lane>>4)*4 + reg, col = lane&15
// Epilogue: i32->f32 convert + per-wave LDS transpose -> float4 stores.
// ---------------------------------------------------------------------------
__global__ __launch_bounds__(256) void gemm_k(
    const uint4* __restrict__ Aq, const uint4* __restrict__ Wq,
    const float* __restrict__ bias, const float* __restrict__ slots,
    float* __restrict__ out) {
  __shared__ float tr[4 * 1280];       // per wave: 64 cols x 20 (16 rows+pad)
  const int tid  = threadIdx.x;
  const int lane = tid & 63;
  const int wid  = tid >> 6;
  const int wm   = wid >> 1;   // 0..1
  const int wn   = wid & 1;    // 0..1
  const int lm   = lane & 15;
  const int lq   = lane >> 4;  // 0..3
  const int m0   = blockIdx.x * 128;   // 392 m-tiles (392%8==0 -> XCD-local)
  const int n0   = blockIdx.y * 128;   // 6 n-tiles

  int abase[4], bbase[4];
#pragma unroll
  for (int tm = 0; tm < 4; ++tm)
    abase[tm] = (m0 + wm * 64 + tm * 16 + lm) * 12 + lq;
#pragma unroll
  for (int tn = 0; tn < 4; ++tn)
    bbase[tn] = (n0 + wn * 64 + tn * 16 + lm) * 12 + lq;

  i32x4 acc[4][4] = {};

#pragma unroll
  for (int ks = 0; ks < 3; ++ks) {     // K=64 per step
    i32x4 af[4], bf[4];
#pragma unroll
    for (int tm = 0; tm < 4; ++tm)
      af[tm] = __builtin_bit_cast(i32x4, Aq[abase[tm] + ks * 4]);
#pragma unroll
    for (int tn = 0; tn < 4; ++tn)
      bf[tn] = __builtin_bit_cast(i32x4, Wq[bbase[tn] + ks * 4]);
#pragma unroll
    for (int tm = 0; tm < 4; ++tm)
#pragma unroll
      for (int tn = 0; tn < 4; ++tn)
        acc[tm][tn] = __builtin_amdgcn_mfma_i32_16x16x64_i8(
            af[tm], bf[tn], acc[tm][tn], 0, 0, 0);
  }

  // ---- epilogue: i32->f32, wave-local transpose, float4 stores ----
  const float scale = slots[0] * slots[1];
  float* T = &tr[wid * 1280];
  const int c4 = lane & 15;                       // float4-column group
  const int gc = n0 + wn * 64 + c4 * 4;
  const float4 bv = *(const float4*)&bias[gc];    // hoisted: c4 fixed per lane

#pragma unroll
  for (int tm = 0; tm < 4; ++tm) {
#pragma unroll
    for (int tn = 0; tn < 4; ++tn) { // element (row=lq*4+j, col=tn*16+lm)
      f32x4 f;
#pragma unroll
      for (int j = 0; j < 4; ++j) f[j] = (float)acc[tm][tn][j];
      *(f32x4*)&T[(tn * 16 + lm) * 20 + lq * 4] = f;
    }
    asm volatile("s_waitcnt lgkmcnt(0)" ::: "memory");
#pragma unroll
    for (int i = 0; i < 4; ++i) {
      const int s = (lane >> 4) + i * 4;          // row 0..15 of this stripe
      float4 v;
      v.x = T[(c4 * 4 + 0) * 20 + s];
      v.y = T[(c4 * 4 + 1) * 20 + s];
      v.z = T[(c4 * 4 + 2) * 20 + s];
      v.w = T[(c4 * 4 + 3) * 20 + s];
      float4 o;
      o.x = fmaf(v.x, scale, bv.x);
      o.y = fmaf(v.y, scale, bv.y);
      o.z = fmaf(v.z, scale, bv.z);
      o.w = fmaf(v.w, scale, bv.w);
      const int gm = m0 + wm * 64 + tm * 16 + s;
      *(float4*)&out[(size_t)gm * 768 + gc] = o;
    }
    asm volatile("s_waitcnt lgkmcnt(0)" ::: "memory");  // drain reads before next tm rewrites T
  }
}

// ---------------------------------------------------------------------------

extern "C" void kernel_launch(void* const* d_in, const int* in_sizes, int n_in,
                              void* d_out, int out_size, void* d_ws, size_t ws_size,
                              hipStream_t stream) {
  const float* xf = (const float*)d_in[0];       // 9,633,792 fp32
  const float4* x4 = (const float4*)d_in[0];
  const float4* w4 = (const float4*)d_in[1];     //   147,456 fp32
  const float* bias = (const float*)d_in[2];     //       768 fp32
  float* out = (float*)d_out;                    // 38,535,168 fp32

  char* ws = (char*)d_ws;
  float* slots    = (float*)ws;                  // [0]=s_x, [1]=s_w
  float* partials = (float*)(ws + 256);          // 1088 floats
  uint4* Wq       = (uint4*)(ws + 8192);         //   147,456 B int8 codes
  uint4* Aq       = (uint4*)(ws + 8192 + 147456);// 9,633,792 B int8 codes

  const int nx4 = 9633792 / 4;   // 2,408,448
  const int nw4 = 147456 / 4;    //    36,864

  absmax_k<<<NBX + NBW, 256, 0, stream>>>(x4, nx4, w4, nw4, partials);
  quant_xw_k<<<NQXB + NQWB, 256, 0, stream>>>(xf, w4, Aq, Wq, partials, slots);
  gemm_k<<<dim3(392, 6), 256, 0, stream>>>(Aq, Wq, bias, slots, out);
}